// Round 1
// baseline (46.088 us; speedup 1.0000x reference)
//
#include <hip/hip_runtime.h>
#include <math.h>

#define BLOCK 256
#define GRID 2048
#define RELEASE_PROB 0.9f

// Pass 1: grid-stride float4 reduction; one partial sum per block into d_ws.
__global__ __launch_bounds__(BLOCK) void neuron_partial(
    const float4* __restrict__ x,
    const float4* __restrict__ w,
    const float4* __restrict__ f,
    const float4* __restrict__ u,
    float* __restrict__ partials,
    int n4)
{
    const int tid = blockIdx.x * BLOCK + threadIdx.x;
    const int stride = GRID * BLOCK;

    float acc = 0.0f;
    for (int i = tid; i < n4; i += stride) {
        const float4 xv = x[i];
        const float4 wv = w[i];
        const float4 fv = f[i];
        const float4 uv = u[i];
        acc += (uv.x < RELEASE_PROB) ? wv.x * fv.x * xv.x : 0.0f;
        acc += (uv.y < RELEASE_PROB) ? wv.y * fv.y * xv.y : 0.0f;
        acc += (uv.z < RELEASE_PROB) ? wv.z * fv.z * xv.z : 0.0f;
        acc += (uv.w < RELEASE_PROB) ? wv.w * fv.w * xv.w : 0.0f;
    }

    // wave64 butterfly reduce
    #pragma unroll
    for (int off = 32; off > 0; off >>= 1)
        acc += __shfl_down(acc, off, 64);

    __shared__ float sm[BLOCK / 64];
    const int lane = threadIdx.x & 63;
    const int wave = threadIdx.x >> 6;
    if (lane == 0) sm[wave] = acc;
    __syncthreads();

    if (threadIdx.x == 0) {
        float s = 0.0f;
        #pragma unroll
        for (int i = 0; i < BLOCK / 64; ++i) s += sm[i];
        partials[blockIdx.x] = s;
    }
}

// Pass 2: single block reduces GRID partials, applies threshold + tanh.
__global__ __launch_bounds__(BLOCK) void neuron_final(
    const float* __restrict__ partials,
    const float* __restrict__ threshold,
    float* __restrict__ out)
{
    float acc = 0.0f;
    for (int i = threadIdx.x; i < GRID; i += BLOCK)
        acc += partials[i];

    #pragma unroll
    for (int off = 32; off > 0; off >>= 1)
        acc += __shfl_down(acc, off, 64);

    __shared__ float sm[BLOCK / 64];
    const int lane = threadIdx.x & 63;
    const int wave = threadIdx.x >> 6;
    if (lane == 0) sm[wave] = acc;
    __syncthreads();

    if (threadIdx.x == 0) {
        float total = 0.0f;
        #pragma unroll
        for (int i = 0; i < BLOCK / 64; ++i) total += sm[i];
        out[0] = (total > threshold[0]) ? tanhf(total) : 0.0f;
    }
}

extern "C" void kernel_launch(void* const* d_in, const int* in_sizes, int n_in,
                              void* d_out, int out_size, void* d_ws, size_t ws_size,
                              hipStream_t stream)
{
    const float* x   = (const float*)d_in[0];
    const float* w   = (const float*)d_in[1];
    const float* f   = (const float*)d_in[2];
    const float* u   = (const float*)d_in[3];
    const float* thr = (const float*)d_in[4];

    float* out = (float*)d_out;
    float* partials = (float*)d_ws;  // GRID floats of scratch

    const int n  = in_sizes[0];      // 16777216, divisible by 4
    const int n4 = n / 4;

    neuron_partial<<<GRID, BLOCK, 0, stream>>>(
        (const float4*)x, (const float4*)w, (const float4*)f, (const float4*)u,
        partials, n4);

    neuron_final<<<1, BLOCK, 0, stream>>>(partials, thr, out);
}